// Round 11
// baseline (190.096 us; speedup 1.0000x reference)
//
#include <hip/hip_runtime.h>

#define N_NODES 50000
#define N_EDGES 625000
#define DIM 128
#define CAP 64            // bucket capacity per node; max degree ~29 (Poisson 12.5)

typedef __bf16 bf16x8 __attribute__((ext_vector_type(8)));
typedef __bf16 bf16x4 __attribute__((ext_vector_type(4)));
typedef __bf16 bf16x2 __attribute__((ext_vector_type(2)));
typedef float f32x4 __attribute__((ext_vector_type(4)));

__device__ __forceinline__ float bflo(unsigned u) { return __uint_as_float(u << 16); }
__device__ __forceinline__ float bfhi(unsigned u) { return __uint_as_float(u & 0xffff0000u); }

// ===========================================================================
// K1: fused [GEMM1 | bucket-CSR fill], 512-thread blocks. (R10 structure)
// First fill block additionally: zeroes h row N_NODES (branchless-gather
// target) and converts W_phy fp32 -> bf16 into Wb (used by K2's MFMA phase,
// read straight from L2 -- no LDS staging in K2).
// ===========================================================================
__global__ __launch_bounds__(512) void gemm1_fill_k(
    const float* __restrict__ A_f32,
    const float* __restrict__ W,
    const float* __restrict__ bias,
    __bf16* __restrict__ out_bf16,
    const int* __restrict__ src,
    const int* __restrict__ dst,
    int* __restrict__ cnt,
    int* __restrict__ bucket,
    const float* __restrict__ W_phy,
    __bf16* __restrict__ Wb,
    int gemm_blocks)
{
    const int t = threadIdx.x;

    if ((int)blockIdx.x >= gemm_blocks) {
        if ((int)blockIdx.x == gemm_blocks) {
            if (t < 16) {
                bf16x8 z = {};
                *(bf16x8*)&out_bf16[(size_t)N_NODES * DIM + t * 8] = z;
            }
            // W_phy fp32 -> bf16 (row-major [n][k], stride 128)
            for (int i = t; i < 4096; i += 512) {
                float4 f = ((const float4*)W_phy)[i];
                bf16x4 pk = { (__bf16)f.x, (__bf16)f.y, (__bf16)f.z, (__bf16)f.w };
                *(bf16x4*)&Wb[i * 4] = pk;
            }
        }
        int idx = ((int)blockIdx.x - gemm_blocks) * 512 + t;
        if (idx < N_EDGES / 4) {
            int4 s4 = ((const int4*)src)[idx];
            int4 d4 = ((const int4*)dst)[idx];
            int p0 = atomicAdd(&cnt[d4.x], 1);
            bucket[(d4.x << 6) + p0] = s4.x;
            int p1 = atomicAdd(&cnt[d4.y], 1);
            bucket[(d4.y << 6) + p1] = s4.y;
            int p2 = atomicAdd(&cnt[d4.z], 1);
            bucket[(d4.z << 6) + p2] = s4.z;
            int p3 = atomicAdd(&cnt[d4.w], 1);
            bucket[(d4.w << 6) + p3] = s4.w;
        }
        return;
    }

    __shared__ __align__(16) __bf16 w_lds[128 * 136];   // 34.8 KB

    for (int i = t; i < 4096; i += 512) {               // 8 iters
        float4 f = ((const float4*)W)[i];
        int n = i >> 5;
        int k = (i & 31) << 2;
        bf16x4 pk = { (__bf16)f.x, (__bf16)f.y, (__bf16)f.z, (__bf16)f.w };
        *(bf16x4*)&w_lds[n * 136 + k] = pk;             // ds_write_b64
    }
    __syncthreads();

    const int wave = t >> 6;           // 0..7
    const int lane = t & 63;
    const int q = lane >> 4;
    const int mr = lane & 15;

    const int m0 = blockIdx.x * 128 + wave * 16;
    int arow = m0 + mr;
    if (arow >= N_NODES) arow = N_NODES - 1;

    f32x4 acc[8] = {};

#pragma unroll
    for (int ks = 0; ks < 4; ++ks) {
        const int k0 = ks * 32 + q * 8;
        const float4* ap = (const float4*)&A_f32[(size_t)arow * DIM + k0];
        float4 a0 = ap[0], a1 = ap[1];
        bf16x8 af;
        af[0] = (__bf16)a0.x; af[1] = (__bf16)a0.y;
        af[2] = (__bf16)a0.z; af[3] = (__bf16)a0.w;
        af[4] = (__bf16)a1.x; af[5] = (__bf16)a1.y;
        af[6] = (__bf16)a1.z; af[7] = (__bf16)a1.w;
#pragma unroll
        for (int nt = 0; nt < 8; ++nt) {
            bf16x8 bfr = *(const bf16x8*)&w_lds[(nt * 16 + mr) * 136 + k0];
            acc[nt] = __builtin_amdgcn_mfma_f32_16x16x32_bf16(af, bfr, acc[nt], 0, 0, 0);
        }
    }

    __syncthreads();                   // all w_lds reads done
    float* lds_f = (float*)w_lds;      // 64 x 132 fp32 buffer
    const int nb = blockIdx.x * 128;

#pragma unroll
    for (int half = 0; half < 2; ++half) {
        if ((wave >> 2) == half) {
            int lw = wave & 3;
#pragma unroll
            for (int nt = 0; nt < 8; ++nt)
#pragma unroll
                for (int r = 0; r < 4; ++r)
                    lds_f[(lw * 16 + q * 4 + r) * 132 + nt * 16 + mr] = acc[nt][r];
        }
        __syncthreads();
        for (int i = t; i < 2048; i += 512) {
            int lr = i >> 5;
            int cg = (i & 31) << 2;
            int grow = nb + half * 64 + lr;
            if (grow < N_NODES) {
                float4 v = *(const float4*)&lds_f[lr * 132 + cg];
                float4 b4 = *(const float4*)&bias[cg];
                bf16x4 o;
                o[0] = (__bf16)fmaxf(v.x + b4.x, 0.f);
                o[1] = (__bf16)fmaxf(v.y + b4.y, 0.f);
                o[2] = (__bf16)fmaxf(v.z + b4.z, 0.f);
                o[3] = (__bf16)fmaxf(v.w + b4.w, 0.f);
                *(bf16x4*)&out_bf16[(size_t)grow * DIM + cg] = o;
            }
        }
        __syncthreads();
    }
}

// ===========================================================================
// K2: fused [aggregate + GIN combine + GEMM2 + bias + relu], done RIGHT:
// Phase A = the proven R9 wave-per-node coalesced gather (each of 4 waves
// aggregates its 16 nodes sequentially; 2 ch/lane; 4-edge unroll; branchless
// via zero row), writing c = bf16(1+eps*h+agg) into a 17.4 KB LDS tile.
// Phase B = MFMA GEMM2 reading A-frags from that LDS tile and B-frags
// DIRECTLY from global bf16 Wb (32 KB, L2-hot -- no W staging at all),
// storing C directly to global in MFMA layout (4x64B segments per store).
// Kills the c HBM round-trip, one dispatch+gap, and 391 W-stagings.
// ===========================================================================
__global__ __launch_bounds__(256) void agg_gemm2_k(
    const __bf16* __restrict__ h,
    const int* __restrict__ cnt,
    const int* __restrict__ bucket,
    const float* __restrict__ eps_p,
    const __bf16* __restrict__ Wb,
    const float* __restrict__ bias,
    float* __restrict__ out)
{
    __shared__ __align__(16) __bf16 c_lds[64 * 136];    // 17.4 KB

    const int t = threadIdx.x;
    const int wave = t >> 6;           // 0..3
    const int lane = t & 63;
    const int ch = lane << 1;          // channels ch, ch+1
    const int nb = blockIdx.x * 64;
    const int ZROW = N_NODES;
    const float eps = eps_p[0];

    // ---- Phase A: aggregate + combine -> c_lds (bf16) ----
    for (int i = 0; i < 16; ++i) {
        int node = nb + wave * 16 + i;
        if (node >= N_NODES) node = N_NODES - 1;
        const int deg = cnt[node];
        const int base = node << 6;

        float ax = 0.f, ay = 0.f;
        for (int e = 0; e < deg; e += 4) {
            uint4 i4 = *(const uint4*)&bucket[base + e];   // broadcast
            int s0 = (int)i4.x;
            int s1 = (e + 1 < deg) ? (int)i4.y : ZROW;
            int s2 = (e + 2 < deg) ? (int)i4.z : ZROW;
            int s3 = (e + 3 < deg) ? (int)i4.w : ZROW;
            unsigned v0 = *(const unsigned*)&h[(size_t)s0 * DIM + ch];
            unsigned v1 = *(const unsigned*)&h[(size_t)s1 * DIM + ch];
            unsigned v2 = *(const unsigned*)&h[(size_t)s2 * DIM + ch];
            unsigned v3 = *(const unsigned*)&h[(size_t)s3 * DIM + ch];
            ax += bflo(v0) + bflo(v1) + bflo(v2) + bflo(v3);
            ay += bfhi(v0) + bfhi(v1) + bfhi(v2) + bfhi(v3);
        }
        unsigned sv = *(const unsigned*)&h[(size_t)node * DIM + ch];
        bf16x2 o;
        o[0] = (__bf16)(1.0f + eps * bflo(sv) + ax);
        o[1] = (__bf16)(1.0f + eps * bfhi(sv) + ay);
        *(bf16x2*)&c_lds[(wave * 16 + i) * 136 + ch] = o;  // conflict-free
    }
    __syncthreads();

    // ---- Phase B: GEMM2 (A from LDS, B from global L2-hot Wb) ----
    const int q = lane >> 4;
    const int mr = lane & 15;

    f32x4 acc[8] = {};
#pragma unroll
    for (int ks = 0; ks < 4; ++ks) {
        const int k0 = ks * 32 + q * 8;
        bf16x8 af = *(const bf16x8*)&c_lds[(wave * 16 + mr) * 136 + k0];
#pragma unroll
        for (int nt = 0; nt < 8; ++nt) {
            bf16x8 bfr = *(const bf16x8*)&Wb[(nt * 16 + mr) * DIM + k0];
            acc[nt] = __builtin_amdgcn_mfma_f32_16x16x32_bf16(af, bfr, acc[nt], 0, 0, 0);
        }
    }

    // Direct C-layout store: row = m0 + q*4 + r, col = nt*16 + mr.
    const int m0 = nb + wave * 16;
#pragma unroll
    for (int nt = 0; nt < 8; ++nt) {
        float b = bias[nt * 16 + mr];
#pragma unroll
        for (int r = 0; r < 4; ++r) {
            int grow = m0 + q * 4 + r;
            if (grow < N_NODES)
                out[(size_t)grow * DIM + nt * 16 + mr] = fmaxf(acc[nt][r] + b, 0.f);
        }
    }
}

extern "C" void kernel_launch(void* const* d_in, const int* in_sizes, int n_in,
                              void* d_out, int out_size, void* d_ws, size_t ws_size,
                              hipStream_t stream) {
    const float* feats = (const float*)d_in[0];
    const int*   src   = (const int*)d_in[1];
    const int*   dst   = (const int*)d_in[2];
    const float* W_f   = (const float*)d_in[3];
    const float* b_f   = (const float*)d_in[4];
    const float* W_phy = (const float*)d_in[5];
    const float* b_phy = (const float*)d_in[6];
    const float* eps   = (const float*)d_in[7];
    float* out = (float*)d_out;

    const size_t HN = (size_t)(N_NODES + 1) * DIM;      // +1 zero row
    __bf16* h   = (__bf16*)d_ws;                        // 12.8 MB
    int* bucket = (int*)(h + HN);                       // 12.8 MB
    int* cnt    = bucket + (size_t)N_NODES * CAP;       // 200 KB
    __bf16* Wb  = (__bf16*)(cnt + N_NODES);             // 32 KB

    const int gblocks = (N_NODES + 127) / 128;          // 391 (K1 gemm part)
    const int fblocks = (N_EDGES / 4 + 511) / 512;      // 306 (K1 fill part)
    const int ablocks = (N_NODES + 63) / 64;            // 782 (K2)

    hipMemsetAsync(cnt, 0, N_NODES * sizeof(int), stream);

    gemm1_fill_k<<<gblocks + fblocks, 512, 0, stream>>>(
        feats, W_f, b_f, h, src, dst, cnt, bucket, W_phy, Wb, gblocks);

    agg_gemm2_k<<<ablocks, 256, 0, stream>>>(
        h, cnt, bucket, eps, Wb, b_phy, out);
}

// Round 12
// 172.789 us; speedup vs baseline: 1.1002x; 1.1002x over previous
//
#include <hip/hip_runtime.h>

#define N_NODES 50000
#define N_EDGES 625000
#define DIM 128
#define CAP 64            // bucket capacity per node; max degree ~29 (Poisson 12.5)

typedef __bf16 bf16x8 __attribute__((ext_vector_type(8)));
typedef __bf16 bf16x4 __attribute__((ext_vector_type(4)));
typedef __bf16 bf16x2 __attribute__((ext_vector_type(2)));
typedef float f32x4 __attribute__((ext_vector_type(4)));

__device__ __forceinline__ float bflo(unsigned u) { return __uint_as_float(u << 16); }
__device__ __forceinline__ float bfhi(unsigned u) { return __uint_as_float(u & 0xffff0000u); }

// ===========================================================================
// K1: fused [GEMM1 | bucket-CSR fill], 512-thread blocks. (R10 structure)
// First fill block also zeroes h row N_NODES and converts W_phy -> bf16 Wb.
// ===========================================================================
__global__ __launch_bounds__(512) void gemm1_fill_k(
    const float* __restrict__ A_f32,
    const float* __restrict__ W,
    const float* __restrict__ bias,
    __bf16* __restrict__ out_bf16,
    const int* __restrict__ src,
    const int* __restrict__ dst,
    int* __restrict__ cnt,
    int* __restrict__ bucket,
    const float* __restrict__ W_phy,
    __bf16* __restrict__ Wb,
    int gemm_blocks)
{
    const int t = threadIdx.x;

    if ((int)blockIdx.x >= gemm_blocks) {
        if ((int)blockIdx.x == gemm_blocks) {
            if (t < 16) {
                bf16x8 z = {};
                *(bf16x8*)&out_bf16[(size_t)N_NODES * DIM + t * 8] = z;
            }
            for (int i = t; i < 4096; i += 512) {
                float4 f = ((const float4*)W_phy)[i];
                bf16x4 pk = { (__bf16)f.x, (__bf16)f.y, (__bf16)f.z, (__bf16)f.w };
                *(bf16x4*)&Wb[i * 4] = pk;
            }
        }
        int idx = ((int)blockIdx.x - gemm_blocks) * 512 + t;
        if (idx < N_EDGES / 4) {
            int4 s4 = ((const int4*)src)[idx];
            int4 d4 = ((const int4*)dst)[idx];
            int p0 = atomicAdd(&cnt[d4.x], 1);
            bucket[(d4.x << 6) + p0] = s4.x;
            int p1 = atomicAdd(&cnt[d4.y], 1);
            bucket[(d4.y << 6) + p1] = s4.y;
            int p2 = atomicAdd(&cnt[d4.z], 1);
            bucket[(d4.z << 6) + p2] = s4.z;
            int p3 = atomicAdd(&cnt[d4.w], 1);
            bucket[(d4.w << 6) + p3] = s4.w;
        }
        return;
    }

    __shared__ __align__(16) __bf16 w_lds[128 * 136];   // 34.8 KB

    for (int i = t; i < 4096; i += 512) {               // 8 iters
        float4 f = ((const float4*)W)[i];
        int n = i >> 5;
        int k = (i & 31) << 2;
        bf16x4 pk = { (__bf16)f.x, (__bf16)f.y, (__bf16)f.z, (__bf16)f.w };
        *(bf16x4*)&w_lds[n * 136 + k] = pk;             // ds_write_b64
    }
    __syncthreads();

    const int wave = t >> 6;           // 0..7
    const int lane = t & 63;
    const int q = lane >> 4;
    const int mr = lane & 15;

    const int m0 = blockIdx.x * 128 + wave * 16;
    int arow = m0 + mr;
    if (arow >= N_NODES) arow = N_NODES - 1;

    f32x4 acc[8] = {};

#pragma unroll
    for (int ks = 0; ks < 4; ++ks) {
        const int k0 = ks * 32 + q * 8;
        const float4* ap = (const float4*)&A_f32[(size_t)arow * DIM + k0];
        float4 a0 = ap[0], a1 = ap[1];
        bf16x8 af;
        af[0] = (__bf16)a0.x; af[1] = (__bf16)a0.y;
        af[2] = (__bf16)a0.z; af[3] = (__bf16)a0.w;
        af[4] = (__bf16)a1.x; af[5] = (__bf16)a1.y;
        af[6] = (__bf16)a1.z; af[7] = (__bf16)a1.w;
#pragma unroll
        for (int nt = 0; nt < 8; ++nt) {
            bf16x8 bfr = *(const bf16x8*)&w_lds[(nt * 16 + mr) * 136 + k0];
            acc[nt] = __builtin_amdgcn_mfma_f32_16x16x32_bf16(af, bfr, acc[nt], 0, 0, 0);
        }
    }

    __syncthreads();                   // all w_lds reads done
    float* lds_f = (float*)w_lds;      // 64 x 132 fp32 buffer
    const int nb = blockIdx.x * 128;

#pragma unroll
    for (int half = 0; half < 2; ++half) {
        if ((wave >> 2) == half) {
            int lw = wave & 3;
#pragma unroll
            for (int nt = 0; nt < 8; ++nt)
#pragma unroll
                for (int r = 0; r < 4; ++r)
                    lds_f[(lw * 16 + q * 4 + r) * 132 + nt * 16 + mr] = acc[nt][r];
        }
        __syncthreads();
        for (int i = t; i < 2048; i += 512) {
            int lr = i >> 5;
            int cg = (i & 31) << 2;
            int grow = nb + half * 64 + lr;
            if (grow < N_NODES) {
                float4 v = *(const float4*)&lds_f[lr * 132 + cg];
                float4 b4 = *(const float4*)&bias[cg];
                bf16x4 o;
                o[0] = (__bf16)fmaxf(v.x + b4.x, 0.f);
                o[1] = (__bf16)fmaxf(v.y + b4.y, 0.f);
                o[2] = (__bf16)fmaxf(v.z + b4.z, 0.f);
                o[3] = (__bf16)fmaxf(v.w + b4.w, 0.f);
                *(bf16x4*)&out_bf16[(size_t)grow * DIM + cg] = o;
            }
        }
        __syncthreads();
    }
}

// ===========================================================================
// K2: aggregate + GIN combine (R9/R10-proven: one wave per node, max TLP).
// Writes c = bf16(1 + eps*h_self + sum_neigh h).
// ===========================================================================
__global__ __launch_bounds__(256) void agg_combine_k(
    const __bf16* __restrict__ h,
    const int* __restrict__ cnt,
    const int* __restrict__ bucket,
    const float* __restrict__ eps_p,
    __bf16* __restrict__ c)
{
    const int t = threadIdx.x;
    const int node = blockIdx.x * 4 + (t >> 6);
    const int lane = t & 63;
    const int ch = lane << 1;

    const int deg = cnt[node];
    const int base = node << 6;
    const int ZROW = N_NODES;

    float ax = 0.f, ay = 0.f;
    for (int e = 0; e < deg; e += 4) {
        uint4 i4 = *(const uint4*)&bucket[base + e];   // broadcast
        int s0 = (int)i4.x;
        int s1 = (e + 1 < deg) ? (int)i4.y : ZROW;
        int s2 = (e + 2 < deg) ? (int)i4.z : ZROW;
        int s3 = (e + 3 < deg) ? (int)i4.w : ZROW;
        unsigned v0 = *(const unsigned*)&h[(size_t)s0 * DIM + ch];
        unsigned v1 = *(const unsigned*)&h[(size_t)s1 * DIM + ch];
        unsigned v2 = *(const unsigned*)&h[(size_t)s2 * DIM + ch];
        unsigned v3 = *(const unsigned*)&h[(size_t)s3 * DIM + ch];
        ax += bflo(v0) + bflo(v1) + bflo(v2) + bflo(v3);
        ay += bfhi(v0) + bfhi(v1) + bfhi(v2) + bfhi(v3);
    }

    const float eps = eps_p[0];
    unsigned sv = *(const unsigned*)&h[(size_t)node * DIM + ch];
    bf16x2 o;
    o[0] = (__bf16)(1.0f + eps * bflo(sv) + ax);
    o[1] = (__bf16)(1.0f + eps * bfhi(sv) + ay);
    *(bf16x2*)&c[(size_t)node * DIM + ch] = o;
}

// ===========================================================================
// K3: LITE bf16 GEMM2 (R11-validated phase-B structure): no LDS at all.
// A-frags from global c; B-frags from global Wb (32 KB, L1-resident);
// direct C-layout store (row = m0+q*4+r, col = nt*16+mr). Low VGPR ->
// high occupancy; no staging, no barriers.
// ===========================================================================
__global__ __launch_bounds__(256) void gemm2_lite_k(
    const __bf16* __restrict__ A,
    const __bf16* __restrict__ Wb,
    const float* __restrict__ bias,
    float* __restrict__ out)
{
    const int t = threadIdx.x;
    const int wave = t >> 6;
    const int lane = t & 63;
    const int q = lane >> 4;
    const int mr = lane & 15;

    const int m0 = blockIdx.x * 64 + wave * 16;
    int arow = m0 + mr;
    if (arow >= N_NODES) arow = N_NODES - 1;

    f32x4 acc[8] = {};
#pragma unroll
    for (int ks = 0; ks < 4; ++ks) {
        const int k0 = ks * 32 + q * 8;
        bf16x8 af = *(const bf16x8*)&A[(size_t)arow * DIM + k0];
#pragma unroll
        for (int nt = 0; nt < 8; ++nt) {
            bf16x8 bfr = *(const bf16x8*)&Wb[(nt * 16 + mr) * DIM + k0];
            acc[nt] = __builtin_amdgcn_mfma_f32_16x16x32_bf16(af, bfr, acc[nt], 0, 0, 0);
        }
    }

#pragma unroll
    for (int nt = 0; nt < 8; ++nt) {
        float b = bias[nt * 16 + mr];
#pragma unroll
        for (int r = 0; r < 4; ++r) {
            int grow = m0 + q * 4 + r;
            if (grow < N_NODES)
                out[(size_t)grow * DIM + nt * 16 + mr] = fmaxf(acc[nt][r] + b, 0.f);
        }
    }
}

extern "C" void kernel_launch(void* const* d_in, const int* in_sizes, int n_in,
                              void* d_out, int out_size, void* d_ws, size_t ws_size,
                              hipStream_t stream) {
    const float* feats = (const float*)d_in[0];
    const int*   src   = (const int*)d_in[1];
    const int*   dst   = (const int*)d_in[2];
    const float* W_f   = (const float*)d_in[3];
    const float* b_f   = (const float*)d_in[4];
    const float* W_phy = (const float*)d_in[5];
    const float* b_phy = (const float*)d_in[6];
    const float* eps   = (const float*)d_in[7];
    float* out = (float*)d_out;

    const size_t HN = (size_t)(N_NODES + 1) * DIM;      // +1 zero row
    __bf16* h   = (__bf16*)d_ws;                        // 12.8 MB
    __bf16* c   = h + HN;                               // 12.8 MB
    int* bucket = (int*)(c + (size_t)N_NODES * DIM);    // 12.8 MB
    int* cnt    = bucket + (size_t)N_NODES * CAP;       // 200 KB
    __bf16* Wb  = (__bf16*)(cnt + N_NODES);             // 32 KB

    const int gblocks = (N_NODES + 127) / 128;          // 391 (K1 gemm part)
    const int fblocks = (N_EDGES / 4 + 511) / 512;      // 306 (K1 fill part)
    const int l_blocks = (N_NODES + 63) / 64;           // 782 (K3)

    hipMemsetAsync(cnt, 0, N_NODES * sizeof(int), stream);

    gemm1_fill_k<<<gblocks + fblocks, 512, 0, stream>>>(
        feats, W_f, b_f, h, src, dst, cnt, bucket, W_phy, Wb, gblocks);

    agg_combine_k<<<N_NODES / 4, 256, 0, stream>>>(
        h, cnt, bucket, eps, c);

    gemm2_lite_k<<<l_blocks, 256, 0, stream>>>(
        c, Wb, b_phy, out);
}

// Round 13
// 161.095 us; speedup vs baseline: 1.1800x; 1.0726x over previous
//
#include <hip/hip_runtime.h>

#define N_NODES 50000
#define N_EDGES 625000
#define DIM 128
#define CAP 64            // bucket capacity per node; max degree ~29 (Poisson 12.5)

typedef __bf16 bf16x8 __attribute__((ext_vector_type(8)));
typedef __bf16 bf16x4 __attribute__((ext_vector_type(4)));
typedef __bf16 bf16x2 __attribute__((ext_vector_type(2)));
typedef float f32x4 __attribute__((ext_vector_type(4)));

__device__ __forceinline__ float bflo(unsigned u) { return __uint_as_float(u << 16); }
__device__ __forceinline__ float bfhi(unsigned u) { return __uint_as_float(u & 0xffff0000u); }

// ===========================================================================
// K1: fused [GEMM1 | bucket-CSR fill], 512-thread blocks (R10 structure).
// First fill block also zeroes h row N_NODES (branchless-gather target) and
// converts W_phy fp32 -> bf16 Wb (consumed by K3's LDS staging).
// ===========================================================================
__global__ __launch_bounds__(512) void gemm1_fill_k(
    const float* __restrict__ A_f32,
    const float* __restrict__ W,
    const float* __restrict__ bias,
    __bf16* __restrict__ out_bf16,
    const int* __restrict__ src,
    const int* __restrict__ dst,
    int* __restrict__ cnt,
    int* __restrict__ bucket,
    const float* __restrict__ W_phy,
    __bf16* __restrict__ Wb,
    int gemm_blocks)
{
    const int t = threadIdx.x;

    if ((int)blockIdx.x >= gemm_blocks) {
        if ((int)blockIdx.x == gemm_blocks) {
            if (t < 16) {
                bf16x8 z = {};
                *(bf16x8*)&out_bf16[(size_t)N_NODES * DIM + t * 8] = z;
            }
            for (int i = t; i < 4096; i += 512) {
                float4 f = ((const float4*)W_phy)[i];
                bf16x4 pk = { (__bf16)f.x, (__bf16)f.y, (__bf16)f.z, (__bf16)f.w };
                *(bf16x4*)&Wb[i * 4] = pk;
            }
        }
        int idx = ((int)blockIdx.x - gemm_blocks) * 512 + t;
        if (idx < N_EDGES / 4) {
            int4 s4 = ((const int4*)src)[idx];
            int4 d4 = ((const int4*)dst)[idx];
            int p0 = atomicAdd(&cnt[d4.x], 1);
            bucket[(d4.x << 6) + p0] = s4.x;
            int p1 = atomicAdd(&cnt[d4.y], 1);
            bucket[(d4.y << 6) + p1] = s4.y;
            int p2 = atomicAdd(&cnt[d4.z], 1);
            bucket[(d4.z << 6) + p2] = s4.z;
            int p3 = atomicAdd(&cnt[d4.w], 1);
            bucket[(d4.w << 6) + p3] = s4.w;
        }
        return;
    }

    __shared__ __align__(16) __bf16 w_lds[128 * 136];   // 34.8 KB

    for (int i = t; i < 4096; i += 512) {               // 8 iters
        float4 f = ((const float4*)W)[i];
        int n = i >> 5;
        int k = (i & 31) << 2;
        bf16x4 pk = { (__bf16)f.x, (__bf16)f.y, (__bf16)f.z, (__bf16)f.w };
        *(bf16x4*)&w_lds[n * 136 + k] = pk;             // ds_write_b64
    }
    __syncthreads();

    const int wave = t >> 6;           // 0..7
    const int lane = t & 63;
    const int q = lane >> 4;
    const int mr = lane & 15;

    const int m0 = blockIdx.x * 128 + wave * 16;
    int arow = m0 + mr;
    if (arow >= N_NODES) arow = N_NODES - 1;

    f32x4 acc[8] = {};

#pragma unroll
    for (int ks = 0; ks < 4; ++ks) {
        const int k0 = ks * 32 + q * 8;
        const float4* ap = (const float4*)&A_f32[(size_t)arow * DIM + k0];
        float4 a0 = ap[0], a1 = ap[1];
        bf16x8 af;
        af[0] = (__bf16)a0.x; af[1] = (__bf16)a0.y;
        af[2] = (__bf16)a0.z; af[3] = (__bf16)a0.w;
        af[4] = (__bf16)a1.x; af[5] = (__bf16)a1.y;
        af[6] = (__bf16)a1.z; af[7] = (__bf16)a1.w;
#pragma unroll
        for (int nt = 0; nt < 8; ++nt) {
            bf16x8 bfr = *(const bf16x8*)&w_lds[(nt * 16 + mr) * 136 + k0];
            acc[nt] = __builtin_amdgcn_mfma_f32_16x16x32_bf16(af, bfr, acc[nt], 0, 0, 0);
        }
    }

    __syncthreads();                   // all w_lds reads done
    float* lds_f = (float*)w_lds;      // 64 x 132 fp32 buffer
    const int nb = blockIdx.x * 128;

#pragma unroll
    for (int half = 0; half < 2; ++half) {
        if ((wave >> 2) == half) {
            int lw = wave & 3;
#pragma unroll
            for (int nt = 0; nt < 8; ++nt)
#pragma unroll
                for (int r = 0; r < 4; ++r)
                    lds_f[(lw * 16 + q * 4 + r) * 132 + nt * 16 + mr] = acc[nt][r];
        }
        __syncthreads();
        for (int i = t; i < 2048; i += 512) {
            int lr = i >> 5;
            int cg = (i & 31) << 2;
            int grow = nb + half * 64 + lr;
            if (grow < N_NODES) {
                float4 v = *(const float4*)&lds_f[lr * 132 + cg];
                float4 b4 = *(const float4*)&bias[cg];
                bf16x4 o;
                o[0] = (__bf16)fmaxf(v.x + b4.x, 0.f);
                o[1] = (__bf16)fmaxf(v.y + b4.y, 0.f);
                o[2] = (__bf16)fmaxf(v.z + b4.z, 0.f);
                o[3] = (__bf16)fmaxf(v.w + b4.w, 0.f);
                *(bf16x4*)&out_bf16[(size_t)grow * DIM + cg] = o;
            }
        }
        __syncthreads();
    }
}

// ===========================================================================
// K2: aggregate + GIN combine (R9/R10-proven: one wave per node, max TLP).
// Writes c = bf16(1 + eps*h_self + sum_neigh h).
// ===========================================================================
__global__ __launch_bounds__(256) void agg_combine_k(
    const __bf16* __restrict__ h,
    const int* __restrict__ cnt,
    const int* __restrict__ bucket,
    const float* __restrict__ eps_p,
    __bf16* __restrict__ c)
{
    const int t = threadIdx.x;
    const int node = blockIdx.x * 4 + (t >> 6);
    const int lane = t & 63;
    const int ch = lane << 1;

    const int deg = cnt[node];
    const int base = node << 6;
    const int ZROW = N_NODES;

    float ax = 0.f, ay = 0.f;
    for (int e = 0; e < deg; e += 4) {
        uint4 i4 = *(const uint4*)&bucket[base + e];   // broadcast
        int s0 = (int)i4.x;
        int s1 = (e + 1 < deg) ? (int)i4.y : ZROW;
        int s2 = (e + 2 < deg) ? (int)i4.z : ZROW;
        int s3 = (e + 3 < deg) ? (int)i4.w : ZROW;
        unsigned v0 = *(const unsigned*)&h[(size_t)s0 * DIM + ch];
        unsigned v1 = *(const unsigned*)&h[(size_t)s1 * DIM + ch];
        unsigned v2 = *(const unsigned*)&h[(size_t)s2 * DIM + ch];
        unsigned v3 = *(const unsigned*)&h[(size_t)s3 * DIM + ch];
        ax += bflo(v0) + bflo(v1) + bflo(v2) + bflo(v3);
        ay += bfhi(v0) + bfhi(v1) + bfhi(v2) + bfhi(v3);
    }

    const float eps = eps_p[0];
    unsigned sv = *(const unsigned*)&h[(size_t)node * DIM + ch];
    bf16x2 o;
    o[0] = (__bf16)(1.0f + eps * bflo(sv) + ax);
    o[1] = (__bf16)(1.0f + eps * bfhi(sv) + ay);
    *(bf16x2*)&c[(size_t)node * DIM + ch] = o;
}

// ===========================================================================
// K3: bf16 MFMA GEMM2 + bias + relu, 512-thread / 128-row blocks (R10
// structure — LDS-staged W, which R12 proved is required: global B-frags in
// the MFMA loop cost 32 VMEM loads/lane and regressed 11 us). Delta vs R10:
// stage from pre-converted bf16 Wb — 4 pure b128 copy iters, half the fetch.
// ===========================================================================
__global__ __launch_bounds__(512) void gemm2_k(
    const __bf16* __restrict__ A,
    const __bf16* __restrict__ Wb,
    const float* __restrict__ bias,
    float* __restrict__ out)
{
    __shared__ __align__(16) __bf16 w_lds[128 * 136];   // 34.8 KB

    const int t = threadIdx.x;

    for (int i = t; i < 2048; i += 512) {               // 4 iters, b128 copy
        int n = i >> 4;
        int kk = (i & 15) << 3;
        bf16x8 v = *(const bf16x8*)&Wb[n * DIM + kk];
        *(bf16x8*)&w_lds[n * 136 + kk] = v;
    }
    __syncthreads();

    const int wave = t >> 6;
    const int lane = t & 63;
    const int q = lane >> 4;
    const int mr = lane & 15;

    const int m0 = blockIdx.x * 128 + wave * 16;
    int arow = m0 + mr;
    if (arow >= N_NODES) arow = N_NODES - 1;

    f32x4 acc[8] = {};

#pragma unroll
    for (int ks = 0; ks < 4; ++ks) {
        const int k0 = ks * 32 + q * 8;
        bf16x8 af = *(const bf16x8*)&A[(size_t)arow * DIM + k0];
#pragma unroll
        for (int nt = 0; nt < 8; ++nt) {
            bf16x8 bfr = *(const bf16x8*)&w_lds[(nt * 16 + mr) * 136 + k0];
            acc[nt] = __builtin_amdgcn_mfma_f32_16x16x32_bf16(af, bfr, acc[nt], 0, 0, 0);
        }
    }

    __syncthreads();
    float* lds_f = (float*)w_lds;      // 64 x 132 fp32
    const int nb = blockIdx.x * 128;

#pragma unroll
    for (int half = 0; half < 2; ++half) {
        if ((wave >> 2) == half) {
            int lw = wave & 3;
#pragma unroll
            for (int nt = 0; nt < 8; ++nt)
#pragma unroll
                for (int r = 0; r < 4; ++r)
                    lds_f[(lw * 16 + q * 4 + r) * 132 + nt * 16 + mr] = acc[nt][r];
        }
        __syncthreads();
        for (int i = t; i < 2048; i += 512) {
            int lr = i >> 5;
            int cg = (i & 31) << 2;
            int grow = nb + half * 64 + lr;
            if (grow < N_NODES) {
                float4 v = *(const float4*)&lds_f[lr * 132 + cg];
                float4 b4 = *(const float4*)&bias[cg];
                v.x = fmaxf(v.x + b4.x, 0.f);
                v.y = fmaxf(v.y + b4.y, 0.f);
                v.z = fmaxf(v.z + b4.z, 0.f);
                v.w = fmaxf(v.w + b4.w, 0.f);
                *(float4*)&out[(size_t)grow * DIM + cg] = v;
            }
        }
        __syncthreads();
    }
}

extern "C" void kernel_launch(void* const* d_in, const int* in_sizes, int n_in,
                              void* d_out, int out_size, void* d_ws, size_t ws_size,
                              hipStream_t stream) {
    const float* feats = (const float*)d_in[0];
    const int*   src   = (const int*)d_in[1];
    const int*   dst   = (const int*)d_in[2];
    const float* W_f   = (const float*)d_in[3];
    const float* b_f   = (const float*)d_in[4];
    const float* W_phy = (const float*)d_in[5];
    const float* b_phy = (const float*)d_in[6];
    const float* eps   = (const float*)d_in[7];
    float* out = (float*)d_out;

    const size_t HN = (size_t)(N_NODES + 1) * DIM;      // +1 zero row
    __bf16* h   = (__bf16*)d_ws;                        // 12.8 MB
    __bf16* c   = h + HN;                               // 12.8 MB
    int* bucket = (int*)(c + (size_t)N_NODES * DIM);    // 12.8 MB
    int* cnt    = bucket + (size_t)N_NODES * CAP;       // 200 KB
    __bf16* Wb  = (__bf16*)(cnt + N_NODES);             // 32 KB

    const int gblocks = (N_NODES + 127) / 128;          // 391 (K1 gemm part)
    const int fblocks = (N_EDGES / 4 + 511) / 512;      // 306 (K1 fill part)

    hipMemsetAsync(cnt, 0, N_NODES * sizeof(int), stream);

    gemm1_fill_k<<<gblocks + fblocks, 512, 0, stream>>>(
        feats, W_f, b_f, h, src, dst, cnt, bucket, W_phy, Wb, gblocks);

    agg_combine_k<<<N_NODES / 4, 256, 0, stream>>>(
        h, cnt, bucket, eps, c);

    gemm2_k<<<gblocks, 512, 0, stream>>>(
        c, Wb, b_phy, out);
}